// Round 3
// baseline (147.276 us; speedup 1.0000x reference)
//
#include <hip/hip_runtime.h>

// (B,N,F,K) = (4096, 2048, 64, 64)
#define NB 4096
#define NN 2048
#define NF 64
#define NK 64
#define NCH 32          // i-chunks of 64 columns
#define NRG 16          // row-groups of 256 rows

// ws layout (float offsets); total ~35 MB, ws_size is 268 MB
#define WS_VG     0                           // Vg   [2048*64]
#define WS_VNORM  (WS_VG + NN * NK)           // vnorm[2048]
#define WS_LINP   (WS_VNORM + NN)             // linp [32][4096]
#define WS_DDP    (WS_LINP + NCH * NB)        // ddp  [32][4096]
#define WS_SROW   (WS_DDP + NCH * NB)         // srow [4096]
#define WS_LINT   (WS_SROW + NB)              // lint [4096]
#define WS_T      (WS_LINT + NB)              // Tp   [32][4096][64]

// ---------- k_prep: gather Vg + vnorm (coalesced, one wave per feature) ----------
__global__ __launch_bounds__(256) void k_prep(const float* __restrict__ vec,
                                              const int* __restrict__ f2f,
                                              float* __restrict__ Vg,
                                              float* __restrict__ vnorm) {
    int i    = (blockIdx.x * 256 + threadIdx.x) >> 6;   // feature row 0..2047
    int lane = threadIdx.x & 63;                        // k
    int f = f2f[i];
    float v = vec[(size_t)i * (NF * NK) + (size_t)f * NK + lane];
    Vg[(size_t)i * NK + lane] = v;                      // 256B coalesced per wave
    float sq = v * v;
    #pragma unroll
    for (int m = 32; m; m >>= 1) sq += __shfl_xor(sq, m, 64);
    if (lane == 0) vnorm[i] = sq;
}

// ---------- k_main: register-streaming GEMM chunk, V via scalar (s_load) path ----------
// thread = one batch row; block = 256 rows x one 64-wide i-chunk; grid = 16 x 32 = 512.
// No LDS, no barriers: X segment (64 floats, 256B contiguous per thread) lives in VGPRs.
__global__ __launch_bounds__(256) void k_main(const float* __restrict__ X,
                                              const float* __restrict__ Wg,
                                              const float* __restrict__ Vg,
                                              const float* __restrict__ vn,
                                              float* __restrict__ Tp,
                                              float* __restrict__ linp,
                                              float* __restrict__ ddp) {
    const int t   = threadIdx.x;
    const int rg  = blockIdx.x >> 5;        // 0..15
    const int c   = blockIdx.x & 31;        // 0..31  (same-c blocks share an XCD: V L2 reuse)
    const int row = rg * 256 + t;
    const int i0  = c * 64;

    const float4* __restrict__ xr = reinterpret_cast<const float4*>(
        X + (size_t)row * NN + i0);
    const float* __restrict__ vb = Vg + (size_t)i0 * NK;   // wave-uniform -> s_load
    const float* __restrict__ wb = Wg + i0;                // wave-uniform
    const float* __restrict__ nb = vn + i0;                // wave-uniform

    // preload the whole 64-float X segment (4 full 64B lines per thread)
    float4 xv[16];
    #pragma unroll
    for (int j = 0; j < 16; ++j) xv[j] = xr[j];

    float acc[NK];
    #pragma unroll
    for (int k = 0; k < NK; ++k) acc[k] = 0.f;
    float lin = 0.f, dd = 0.f;

    #pragma unroll
    for (int j = 0; j < 16; ++j) {
        float xs0 = xv[j].x, xs1 = xv[j].y, xs2 = xv[j].z, xs3 = xv[j].w;
        #pragma unroll
        for (int e = 0; e < 4; ++e) {
            const int i = 4 * j + e;
            float x = (e == 0) ? xs0 : (e == 1) ? xs1 : (e == 2) ? xs2 : xs3;
            lin = fmaf(x, wb[i], lin);
            dd  = fmaf(x * x, nb[i], dd);
            #pragma unroll
            for (int k = 0; k < NK; ++k)
                acc[k] = fmaf(x, vb[i * NK + k], acc[k]);   // SGPR operand
        }
    }

    // epilogue: 256B contiguous per thread (full lines), no transpose needed
    float4* out4 = reinterpret_cast<float4*>(Tp + ((size_t)c * NB + row) * NK);
    #pragma unroll
    for (int k4 = 0; k4 < 16; ++k4)
        out4[k4] = make_float4(acc[4 * k4], acc[4 * k4 + 1],
                               acc[4 * k4 + 2], acc[4 * k4 + 3]);
    linp[c * NB + row] = lin;   // coalesced, no atomics, no memset needed
    ddp [c * NB + row] = dd;
}

// ---------- k_red: reduce chunk partials -> srow, lint ----------
// 16 threads per row: thread (row, g) owns k = 4g..4g+3, sums over 32 chunks.
__global__ __launch_bounds__(256) void k_red(const float* __restrict__ Tp,
                                             const float* __restrict__ linp,
                                             const float* __restrict__ ddp,
                                             float* __restrict__ srow,
                                             float* __restrict__ lint) {
    int gid = blockIdx.x * 256 + threadIdx.x;
    int row = gid >> 4;
    int g   = gid & 15;
    float4 s = {0.f, 0.f, 0.f, 0.f};
    for (int cc = 0; cc < NCH; ++cc) {
        float4 p = *reinterpret_cast<const float4*>(
            Tp + ((size_t)cc * NB + row) * NK + g * 4);
        s.x += p.x; s.y += p.y; s.z += p.z; s.w += p.w;
    }
    float v = s.x * s.x + s.y * s.y + s.z * s.z + s.w * s.w;
    float l = linp[g * NB + row] + linp[(g + 16) * NB + row];
    float d = ddp [g * NB + row] + ddp [(g + 16) * NB + row];
    #pragma unroll
    for (int m = 1; m < 16; m <<= 1) {
        v += __shfl_xor(v, m, 64);
        l += __shfl_xor(l, m, 64);
        d += __shfl_xor(d, m, 64);
    }
    if (g == 0) { srow[row] = v - d; lint[row] = l; }
}

// ---------- k_final: fp64 reduce of srow + broadcast ----------
__global__ __launch_bounds__(256) void k_final(const float* __restrict__ lint,
                                               const float* __restrict__ srow,
                                               const float* __restrict__ bptr,
                                               float* __restrict__ out) {
    __shared__ double red[256];
    int t = threadIdx.x;
    double a = 0.0;
    for (int j = t; j < NB; j += 256) a += (double)srow[j];
    red[t] = a;
    __syncthreads();
    #pragma unroll
    for (int s = 128; s; s >>= 1) {
        if (t < s) red[t] += red[t + s];
        __syncthreads();
    }
    float inter = (float)(0.5 * red[0]);
    float bias  = bptr[0];
    for (int j = t; j < NB; j += 256) out[j] = lint[j] + bias + inter;
}

extern "C" void kernel_launch(void* const* d_in, const int* in_sizes, int n_in,
                              void* d_out, int out_size, void* d_ws, size_t ws_size,
                              hipStream_t stream) {
    const float* X    = (const float*)d_in[0];
    const float* W    = (const float*)d_in[1];
    const float* bias = (const float*)d_in[2];
    const float* vec  = (const float*)d_in[3];
    const int*   f2f  = (const int*)d_in[4];
    float* out = (float*)d_out;

    float* ws    = (float*)d_ws;
    float* Vg    = ws + WS_VG;
    float* vnorm = ws + WS_VNORM;
    float* linp  = ws + WS_LINP;
    float* ddp   = ws + WS_DDP;
    float* srow  = ws + WS_SROW;
    float* lint  = ws + WS_LINT;
    float* Tp    = ws + WS_T;

    k_prep<<<512, 256, 0, stream>>>(vec, f2f, Vg, vnorm);                 // 2048 waves
    k_main<<<NRG * NCH, 256, 0, stream>>>(X, W, Vg, vnorm, Tp, linp, ddp); // 512 blocks
    k_red<<<NB * 16 / 256, 256, 0, stream>>>(Tp, linp, ddp, srow, lint);   // 256 blocks
    k_final<<<1, 256, 0, stream>>>(lint, srow, bias, out);
}

// Round 4
// 127.789 us; speedup vs baseline: 1.1525x; 1.1525x over previous
//
#include <hip/hip_runtime.h>

// (B,N,F,K) = (4096, 2048, 64, 64)
#define NB 4096
#define NN 2048
#define NF 64
#define NK 64

#define NCH 8              // contraction chunks
#define CLEN 256           // contraction cols per chunk (NN/NCH)
#define RPB 64             // rows per block
#define KSTEPS (CLEN / 32) // 8 MFMA K-steps per chunk

typedef short bf16x8 __attribute__((ext_vector_type(8)));  // 8 bf16 (4 VGPRs)
typedef float f32x4  __attribute__((ext_vector_type(4)));

// ws byte offsets (all 256B-aligned)
#define OFF_VGTH 0                          // ushort [64][2048]  hi
#define OFF_VGTL (OFF_VGTH + NK * NN * 2)   // ushort [64][2048]  lo
#define OFF_VN   (OFF_VGTL + NK * NN * 2)   // float  [2048]
#define OFF_LINP (OFF_VN + NN * 4)          // float  [8][4096]
#define OFF_DDP  (OFF_LINP + NCH * NB * 4)  // float  [8][4096]
#define OFF_SROW (OFF_DDP + NCH * NB * 4)   // float  [4096]
#define OFF_LINT (OFF_SROW + NB * 4)        // float  [4096]
#define OFF_TP   (OFF_LINT + NB * 4)        // float  [8][4096][64] = 8 MB

__device__ inline unsigned short bf16_rtn(float f) {
    unsigned u = __float_as_uint(f);
    return (unsigned short)((u + 0x7fffu + ((u >> 16) & 1u)) >> 16);
}

// ---------- k_prep: gather V rows, split to bf16 hi/lo, store TRANSPOSED [k][i] ----------
__global__ __launch_bounds__(256) void k_prep(const float* __restrict__ vec,
                                              const int* __restrict__ f2f,
                                              unsigned short* __restrict__ VgTh,
                                              unsigned short* __restrict__ VgTl,
                                              float* __restrict__ vnorm) {
    __shared__ unsigned short tH[64][72];
    __shared__ unsigned short tL[64][72];
    const int t  = threadIdx.x;
    const int i0 = blockIdx.x * 64;
    // phase 1: thread t loads 16 floats of feature il = t>>2
    {
        const int il = t >> 2;
        const int sg = (t & 3) * 16;
        const int i  = i0 + il;
        const int f  = f2f[i];
        const float* p = vec + (size_t)i * (NF * NK) + (size_t)f * NK + sg;
        float nsum = 0.f;
        #pragma unroll
        for (int j4 = 0; j4 < 4; ++j4) {
            float4 v = *reinterpret_cast<const float4*>(p + j4 * 4);
            float vv[4] = {v.x, v.y, v.z, v.w};
            #pragma unroll
            for (int e = 0; e < 4; ++e) {
                float x = vv[e];
                nsum = fmaf(x, x, nsum);
                unsigned xb = __float_as_uint(x);
                float hf = __uint_as_float(xb & 0xffff0000u);
                int k = sg + j4 * 4 + e;
                tH[il][k] = (unsigned short)(xb >> 16);
                tL[il][k] = bf16_rtn(x - hf);
            }
        }
        nsum += __shfl_xor(nsum, 1, 64);
        nsum += __shfl_xor(nsum, 2, 64);
        if ((t & 3) == 0) vnorm[i] = nsum;   // vnorm from EXACT fp32 values
    }
    __syncthreads();
    // phase 2: thread t writes k-row t>>2, i-segment (t&3)*16 (32B stores)
    {
        const int k  = t >> 2;
        const int is = (t & 3) * 16;
        unsigned short hb[16], lb[16];
        #pragma unroll
        for (int j = 0; j < 16; ++j) { hb[j] = tH[is + j][k]; lb[j] = tL[is + j][k]; }
        unsigned short* ph = VgTh + (size_t)k * NN + i0 + is;
        unsigned short* pl = VgTl + (size_t)k * NN + i0 + is;
        *reinterpret_cast<uint4*>(ph)     = *reinterpret_cast<uint4*>(hb);
        *reinterpret_cast<uint4*>(ph + 8) = *reinterpret_cast<uint4*>(hb + 8);
        *reinterpret_cast<uint4*>(pl)     = *reinterpret_cast<uint4*>(lb);
        *reinterpret_cast<uint4*>(pl + 8) = *reinterpret_cast<uint4*>(lb + 8);
    }
}

// ---------- k_main: MFMA GEMM chunk (bf16 hi/lo x3), fused lin/dd ----------
// block = 64 rows x 256-contraction chunk; wave = one 16-row M-tile, all 4 N-tiles.
__global__ __launch_bounds__(256, 2) void k_main(const float* __restrict__ X,
                                                 const float* __restrict__ Wg,
                                                 const unsigned short* __restrict__ VgTh,
                                                 const unsigned short* __restrict__ VgTl,
                                                 const float* __restrict__ vn,
                                                 float* __restrict__ Tp,
                                                 float* __restrict__ linp,
                                                 float* __restrict__ ddp) {
    const int t    = threadIdx.x;
    const int lane = t & 63;
    const int w    = t >> 6;               // wave = M-tile index
    const int rg   = blockIdx.x >> 3;      // 0..63 row-group
    const int ch   = blockIdx.x & 7;       // 0..7 contraction chunk
    const int r0   = rg * RPB;
    const int c0   = ch * CLEN;

    const int m    = lane & 15;
    const int quad = lane >> 4;
    const int row  = r0 + w * 16 + m;      // this lane's A row

    const float* xp = X  + (size_t)row * NN + c0 + quad * 8;
    const float* wp = Wg + c0 + quad * 8;
    const float* np = vn + c0 + quad * 8;

    f32x4 acc[4];
    #pragma unroll
    for (int nt = 0; nt < 4; ++nt)
        #pragma unroll
        for (int e = 0; e < 4; ++e) acc[nt][e] = 0.f;
    float lin = 0.f, dd = 0.f;

    #pragma unroll
    for (int s = 0; s < KSTEPS; ++s) {
        // ---- load X (8 fp32), W, vn ----
        float4 xa = *reinterpret_cast<const float4*>(xp + s * 32);
        float4 xb = *reinterpret_cast<const float4*>(xp + s * 32 + 4);
        float4 wa = *reinterpret_cast<const float4*>(wp + s * 32);
        float4 wb = *reinterpret_cast<const float4*>(wp + s * 32 + 4);
        float4 na = *reinterpret_cast<const float4*>(np + s * 32);
        float4 nb = *reinterpret_cast<const float4*>(np + s * 32 + 4);

        float xs8[8] = {xa.x, xa.y, xa.z, xa.w, xb.x, xb.y, xb.z, xb.w};
        float ws8[8] = {wa.x, wa.y, wa.z, wa.w, wb.x, wb.y, wb.z, wb.w};
        float ns8[8] = {na.x, na.y, na.z, na.w, nb.x, nb.y, nb.z, nb.w};

        // ---- fused linear + diag (exact fp32 X) ----
        #pragma unroll
        for (int j = 0; j < 8; ++j) {
            lin = fmaf(xs8[j], ws8[j], lin);
            dd  = fmaf(xs8[j] * xs8[j], ns8[j], dd);
        }

        // ---- build A hi/lo frags in-register ----
        bf16x8 ah, al;
        #pragma unroll
        for (int j = 0; j < 8; ++j) {
            unsigned ub = __float_as_uint(xs8[j]);
            ah[j] = (short)(ub >> 16);
            float hf = __uint_as_float(ub & 0xffff0000u);
            al[j] = (short)bf16_rtn(xs8[j] - hf);
        }

        // ---- B frags from pre-split transposed V (L2-hot), 3 MFMAs per N-tile ----
        const size_t boff = (size_t)c0 + s * 32 + quad * 8;
        #pragma unroll
        for (int nt = 0; nt < 4; ++nt) {
            const size_t nrow = (size_t)(nt * 16 + m) * NN + boff;
            bf16x8 bh = *reinterpret_cast<const bf16x8*>(VgTh + nrow);
            bf16x8 bl = *reinterpret_cast<const bf16x8*>(VgTl + nrow);
            acc[nt] = __builtin_amdgcn_mfma_f32_16x16x32_bf16(ah, bh, acc[nt], 0, 0, 0);
            acc[nt] = __builtin_amdgcn_mfma_f32_16x16x32_bf16(al, bh, acc[nt], 0, 0, 0);
            acc[nt] = __builtin_amdgcn_mfma_f32_16x16x32_bf16(ah, bl, acc[nt], 0, 0, 0);
        }
    }

    // ---- lin/dd: reduce across quads (lanes sharing m) ----
    lin += __shfl_xor(lin, 16, 64);
    lin += __shfl_xor(lin, 32, 64);
    dd  += __shfl_xor(dd, 16, 64);
    dd  += __shfl_xor(dd, 32, 64);
    if (quad == 0) {
        linp[ch * NB + row] = lin;
        ddp [ch * NB + row] = dd;
    }

    // ---- Tp store: C-layout row = quad*4+r, col = nt*16+m ----
    float* tb = Tp + (size_t)ch * NB * NK;
    #pragma unroll
    for (int nt = 0; nt < 4; ++nt)
        #pragma unroll
        for (int r = 0; r < 4; ++r) {
            int rr = r0 + w * 16 + quad * 4 + r;
            tb[(size_t)rr * NK + nt * 16 + m] = acc[nt][r];
        }
}

// ---------- k_red: sum 8 chunk partials -> srow, lint ----------
__global__ __launch_bounds__(256) void k_red(const float* __restrict__ Tp,
                                             const float* __restrict__ linp,
                                             const float* __restrict__ ddp,
                                             float* __restrict__ srow,
                                             float* __restrict__ lint) {
    int gid = blockIdx.x * 256 + threadIdx.x;
    int row = gid >> 4;
    int g   = gid & 15;
    float4 s = {0.f, 0.f, 0.f, 0.f};
    #pragma unroll
    for (int cc = 0; cc < NCH; ++cc) {
        float4 p = *reinterpret_cast<const float4*>(
            Tp + ((size_t)cc * NB + row) * NK + g * 4);
        s.x += p.x; s.y += p.y; s.z += p.z; s.w += p.w;
    }
    float v = s.x * s.x + s.y * s.y + s.z * s.z + s.w * s.w;
    float l = (g < NCH) ? linp[g * NB + row] : 0.f;
    float d = (g < NCH) ? ddp [g * NB + row] : 0.f;
    #pragma unroll
    for (int mm = 1; mm < 16; mm <<= 1) {
        v += __shfl_xor(v, mm, 64);
        l += __shfl_xor(l, mm, 64);
        d += __shfl_xor(d, mm, 64);
    }
    if (g == 0) { srow[row] = v - d; lint[row] = l; }
}

// ---------- k_final: fp64 reduce of srow + broadcast ----------
__global__ __launch_bounds__(256) void k_final(const float* __restrict__ lint,
                                               const float* __restrict__ srow,
                                               const float* __restrict__ bptr,
                                               float* __restrict__ out) {
    __shared__ double red[256];
    int t = threadIdx.x;
    double a = 0.0;
    for (int j = t; j < NB; j += 256) a += (double)srow[j];
    red[t] = a;
    __syncthreads();
    #pragma unroll
    for (int s = 128; s; s >>= 1) {
        if (t < s) red[t] += red[t + s];
        __syncthreads();
    }
    float inter = (float)(0.5 * red[0]);
    float bias  = bptr[0];
    for (int j = t; j < NB; j += 256) out[j] = lint[j] + bias + inter;
}

extern "C" void kernel_launch(void* const* d_in, const int* in_sizes, int n_in,
                              void* d_out, int out_size, void* d_ws, size_t ws_size,
                              hipStream_t stream) {
    const float* X    = (const float*)d_in[0];
    const float* W    = (const float*)d_in[1];
    const float* bias = (const float*)d_in[2];
    const float* vec  = (const float*)d_in[3];
    const int*   f2f  = (const int*)d_in[4];
    float* out = (float*)d_out;

    char* base = (char*)d_ws;
    unsigned short* VgTh = (unsigned short*)(base + OFF_VGTH);
    unsigned short* VgTl = (unsigned short*)(base + OFF_VGTL);
    float* vnorm = (float*)(base + OFF_VN);
    float* linp  = (float*)(base + OFF_LINP);
    float* ddp   = (float*)(base + OFF_DDP);
    float* srow  = (float*)(base + OFF_SROW);
    float* lint  = (float*)(base + OFF_LINT);
    float* Tp    = (float*)(base + OFF_TP);

    k_prep<<<NN / 64, 256, 0, stream>>>(vec, f2f, VgTh, VgTl, vnorm);        // 32 blocks
    k_main<<<(NB / RPB) * NCH, 256, 0, stream>>>(X, W, VgTh, VgTl, vnorm,
                                                 Tp, linp, ddp);             // 512 blocks
    k_red<<<NB * 16 / 256, 256, 0, stream>>>(Tp, linp, ddp, srow, lint);     // 256 blocks
    k_final<<<1, 256, 0, stream>>>(lint, srow, bias, out);
}